// Round 10
// baseline (290.856 us; speedup 1.0000x reference)
//
#include <hip/hip_runtime.h>
#include <math.h>

#define NCH 32
#define CHV (64*32*64)      // one channel volume
#define NB 4
#define NT2 512             // tile-slots per n: 32zt * 8yt * 2chh
#define INVC (1.0f/(32.0f+1e-6f))
#define D2R 0.017453292519943295f
#define R2D 57.29577951308232f

// feat1 LDS slab: [8 z][4 y] rows, pitch 69 (odd mod 32 -> scalar bilinear
// reads ~2-way bank spread). Address(row,col) = 1 + row*69 + col.
// Guards zeroed once at init: addr 0 (row0 col -1) and cols 64..68 of every
// row (col 68 of row r == col -1 of row r+1).
#define P1 69
#define BUFSZ (1 + 32*69 + 3)   // 2212 floats per buffer

// ---------------------------------------------------------------------------
// Kernel 1: fused rotate-warp(feat1) x 27-offset correlation vs feat0.
// Block = (b, chh, 2z x 4y x 64x tile): 256 threads.
// Waves 0/1/2 -> rotations (-4deg / identity / +4deg); wave 3 -> dedicated
// feat1 stager (double-buffered, 1 barrier/channel). The stager RECOMPUTES
// its offsets each channel (no persistent arrays -> ~30 fewer VGPRs for
// every wave; the recompute runs on the otherwise-idle stager wave).
// feat0 rows read DIRECT from global (coalesced float4, L1/L2-resident).
// ---------------------------------------------------------------------------
__global__ __launch_bounds__(256) void k_heat(const float* __restrict__ feat0,
                                              const float* __restrict__ feat1,
                                              float* __restrict__ partial)
{
    __shared__ float L[2][BUFSZ];
    __shared__ float red[3][27];

    // XCD-chunked remap: XCD x gets 256 consecutive nids = exactly one (b,chh)
    const int lid = (int)blockIdx.x;            // 0..2047
    const int nid = (lid & 7) * 256 + (lid >> 3);
    const int yt  = nid & 7;
    const int zt  = (nid >> 3) & 31;
    const int chh = (nid >> 8) & 1;
    const int b   = nid >> 9;

    const int tid = (int)threadIdx.x;
    const int wv = tid >> 6;           // 0,1,2 compute rotations; 3 stager
    const int lane = tid & 63;
    const int tx = lane & 15, ty = lane >> 4;
    const int x0 = 4 * tx;
    const int y  = 4 * yt + ty;
    const int z0 = 2 * zt;             // thread owns z0, z0+1
    const bool yedge = (yt == 0) || (yt == 7);

    // zero the 161 never-written guard floats per buffer (addr0 + 5 cols x 32 rows)
    for (int i = tid; i < 322; i += 256) {
        const int bufi = (i >= 161) ? 1 : 0;
        const int j = i - 161 * bufi;
        const int addr = (j == 0) ? 0 : (1 + ((j - 1) / 5) * P1 + 64 + ((j - 1) % 5));
        L[bufi][addr] = 0.0f;
    }

    const float* f0base = feat0 + ((size_t)b * NCH + chh * 16) * CHV;
    const float* f1base = feat1 + ((size_t)b * NCH + chh * 16) * CHV;

    // ---- bilinear setup (channel-invariant), rot waves 0/2 only ----
    float WX0[2][4], WX1[2][4], WZ0[2][4];
    int A[2][4];
    if (wv == 0 || wv == 2) {
        const float th = 4.0f * (float)(wv - 1) * D2R;
        const float cs = cosf(th), sn = sinf(th);
        #pragma unroll
        for (int k = 0; k < 2; ++k) {
            #pragma unroll
            for (int i = 0; i < 4; ++i) {
                const float rx = (float)(x0 + i) - 31.5f;
                const float rz = (float)(z0 + k) - 31.5f;
                const float sx = cs * rx - sn * rz + 31.5f;
                const float sz = sn * rx + cs * rz + 31.5f;
                const float xf = floorf(sx), zf = floorf(sz);
                const float fxv = sx - xf, fzv = sz - zf;
                const int ix = (int)xf, iz = (int)zf;
                WX0[k][i] = ((unsigned)ix < 64u) ? (1.0f - fxv) : 0.0f;
                WX1[k][i] = ((unsigned)(ix + 1) < 64u) ? fxv : 0.0f;
                WZ0[k][i] = 1.0f - fzv;     // z-OOB rows staged as zeros
                const int zl = min(max(iz - (2 * zt - 3), 0), 6);
                const int bx = min(max(ix, -1), 63);
                A[k][i] = 1 + (zl * 4 + ty) * P1 + bx;
            }
        }
    }
    const int iA0 = 1 + (12 + ty) * P1 + x0;      // identity: z0 row (zr=3)
    const int iA1 = iA0 + 4 * P1;                 // identity: z0+1 row (zr=4)

    // y-row masks + clamped offsets incl. x0 (channel-invariant, per lane)
    float myv[3]; int yoffc[3];
    #pragma unroll
    for (int yri = 0; yri < 3; ++yri) {
        const int yy = y - 1 + yri;
        myv[yri] = ((unsigned)yy < 32u) ? 1.0f : 0.0f;
        yoffc[yri] = min(max(yy, 0), 31) * 64 + x0;
    }

    float acc[27];
    #pragma unroll
    for (int o = 0; o < 27; ++o) acc[o] = 0.0f;

// Stager body: recompute chunk mapping from lane each time (no live arrays).
// 544 float4 chunks = [8 z][4 y][17]; chunk 16 of each row is the guard
// (skipped; guards zeroed at init).
#define STAGE_CH(CHN, LDST)                                                     \
    {                                                                           \
        const float* f1c = f1base + (size_t)(CHN) * CHV;                        \
        float* Ln = (LDST);                                                     \
        _Pragma("unroll")                                                       \
        for (int k = 0; k < 9; ++k) {                                           \
            const int f = lane + 64 * k;                                        \
            if (f < 544) {                                                      \
                const int zr = f / 68, fi = f - 68 * zr;                        \
                const int yr = fi / 17, cq = fi - 17 * yr;                      \
                const int zs = 2 * zt - 3 + zr;                                 \
                if (cq < 16) {                                                  \
                    float4 v = {0.0f, 0.0f, 0.0f, 0.0f};                        \
                    if (zs >= 0 && zs < 64)                                     \
                        v = *(const float4*)(f1c + (zs * 2048                   \
                              + (4 * yt + yr) * 64 + 4 * cq));                  \
                    const int w = 1 + (zr * 4 + yr) * P1 + 4 * cq;              \
                    Ln[w + 0] = v.x; Ln[w + 1] = v.y;                           \
                    Ln[w + 2] = v.z; Ln[w + 3] = v.w;                           \
                }                                                               \
            }                                                                   \
        }                                                                       \
    }

    // ---- prologue: stager fills channel 0 into buffer 0 ----
    if (wv == 3) STAGE_CH(0, &L[0][0])
    __syncthreads();

    #pragma unroll 1
    for (int ch = 0; ch < 16; ++ch) {
        if (wv == 3) {
            if (ch + 1 < 16) STAGE_CH(ch + 1, &L[(ch + 1) & 1][0])
        } else {
            const float* Lb = &L[ch & 1][0];

            // ---- featN sample: fr[k][i] for owned voxels ----
            float fr[2][4];
            if (wv == 1) {                 // identity rotation: direct rows
                #pragma unroll
                for (int i = 0; i < 4; ++i) {
                    fr[0][i] = Lb[iA0 + i];
                    fr[1][i] = Lb[iA1 + i];
                }
            } else {
                #pragma unroll
                for (int k = 0; k < 2; ++k) {
                    #pragma unroll
                    for (int i = 0; i < 4; ++i) {
                        const int a = A[k][i];
                        const float p00 = Lb[a], p01 = Lb[a + 1];
                        const float p10 = Lb[a + 4 * P1], p11 = Lb[a + 4 * P1 + 1];
                        const float w0 = WZ0[k][i];
                        const float t = p10 + w0 * (p00 - p10);
                        const float u = p11 + w0 * (p01 - p11);
                        fr[k][i] = WX0[k][i] * t + WX1[k][i] * u;
                    }
                }
            }

            // ---- featN x-extension (4 shuffles/ch, not per-row edges) ----
            float g0[2], g5[2];
            #pragma unroll
            for (int k = 0; k < 2; ++k) {
                const float a = __shfl_up(fr[k][3], 1, 64);
                const float c = __shfl_down(fr[k][0], 1, 64);
                g0[k] = (tx == 0) ? 0.0f : a;     // featN[x=-1] = 0 (pad)
                g5[k] = (tx == 15) ? 0.0f : c;    // featN[x=64] = 0 (pad)
            }

            // ---- correlation: 12 feat0 rows direct from global ----
            const float* f0c = f0base + (size_t)ch * CHV;
#define ROWFMA(KK, OZP1, YRI)                                                   \
            { const int base_ = (OZP1) * 9 + (2 - (YRI)) * 3;                   \
              acc[base_ + 0] += g0[KK]*R.x + fr[KK][0]*R.y + fr[KK][1]*R.z + fr[KK][2]*R.w; \
              acc[base_ + 1] += fr[KK][0]*R.x + fr[KK][1]*R.y + fr[KK][2]*R.z + fr[KK][3]*R.w; \
              acc[base_ + 2] += fr[KK][1]*R.x + fr[KK][2]*R.y + fr[KK][3]*R.z + g5[KK]*R.w; }
#define CORRLOOP(MASKED)                                                        \
            _Pragma("unroll")                                                   \
            for (int zri = 0; zri < 4; ++zri) {                                 \
                const int zz = 2 * zt - 1 + zri;                                \
                if (zz >= 0 && zz <= 63) {                                      \
                    const float* rp = f0c + zz * 2048;                          \
                    _Pragma("unroll")                                           \
                    for (int yri = 0; yri < 3; ++yri) {                         \
                        float4 R = *(const float4*)(rp + yoffc[yri]);           \
                        if (MASKED) { const float m_ = myv[yri];                \
                            R.x *= m_; R.y *= m_; R.z *= m_; R.w *= m_; }       \
                        if (zri == 0) { ROWFMA(0, 2, yri) }                     \
                        if (zri == 1) { ROWFMA(0, 1, yri) ROWFMA(1, 2, yri) }   \
                        if (zri == 2) { ROWFMA(0, 0, yri) ROWFMA(1, 1, yri) }   \
                        if (zri == 3) { ROWFMA(1, 0, yri) }                     \
                    }                                                           \
                }                                                               \
            }
            if (yedge) { CORRLOOP(1) } else { CORRLOOP(0) }
#undef CORRLOOP
#undef ROWFMA
        }
        __syncthreads();
    }

    // ---- per-wave reduction (fixed order -> deterministic) ----
    if (wv < 3) {
        #pragma unroll 1
        for (int o = 0; o < 27; ++o) {
            float v = acc[o];
            #pragma unroll
            for (int d = 32; d >= 1; d >>= 1) v += __shfl_down(v, d, 64);
            if (lane == 0) red[wv][o] = v;
        }
    }
    __syncthreads();
    if (tid < 81) {
        const int rr = tid / 27, o = tid - rr * 27;
        const int slot = (zt * 8 + yt) * 2 + chh;
        partial[((size_t)((b * 3 + rr) * 27) + o) * NT2 + slot] = red[rr][o];
    }
}

// ---------------------------------------------------------------------------
// Kernel 2: reduce partials (transposed layout: [n*27][512] rows, vectorized)
// -> heat, per-batch MLP, loss + matrices + params.
// ---------------------------------------------------------------------------
__global__ __launch_bounds__(256) void k_mlp(const float* __restrict__ partial,
                                             const float* __restrict__ camg,
                                             const float* __restrict__ W1,
                                             const float* __restrict__ b1,
                                             const float* __restrict__ W2,
                                             const float* __restrict__ b2,
                                             const float* __restrict__ W3,
                                             const float* __restrict__ b3,
                                             float* __restrict__ out,
                                             float* __restrict__ params)
{
    __shared__ float heat[324];
    __shared__ float f[81];
    __shared__ float h1[128];
    __shared__ float h2[128];
    __shared__ float denom_s;
    __shared__ float res[NB][8];
    const int tid = (int)threadIdx.x;

    for (int r = tid; r < 324; r += 256) {
        const float4* p = (const float4*)(partial + (size_t)r * NT2);
        float s0 = 0.0f, s1 = 0.0f, s2 = 0.0f, s3 = 0.0f;
        #pragma unroll 4
        for (int i = 0; i < NT2 / 4; ++i) {
            const float4 v = p[i];
            s0 += v.x; s1 += v.y; s2 += v.z; s3 += v.w;
        }
        heat[r] = ((s0 + s1) + (s2 + s3)) * INVC;
    }
    __syncthreads();

    for (int b = 0; b < NB; ++b) {
        if (tid < 81) {
            float v = heat[b * 81 + tid];
            f[tid] = (v >= 0.0f) ? v : 0.1f * v;
        }
        __syncthreads();
        if (tid == 0) {
            float ss = 0.0f;
            for (int k = 0; k < 81; ++k) ss += f[k] * f[k];
            denom_s = 1e-6f + sqrtf(ss);
        }
        __syncthreads();
        if (tid < 81) f[tid] = f[tid] / denom_s;
        __syncthreads();
        if (tid < 128) {
            float a = b1[tid];
            const float* wr = W1 + tid * 81;
            for (int k = 0; k < 81; ++k) a += wr[k] * f[k];
            h1[tid] = (a >= 0.0f) ? a : 0.1f * a;
        }
        __syncthreads();
        if (tid < 128) {
            float a = b2[tid];
            const float* wr = W2 + tid * 128;
            for (int k = 0; k < 128; ++k) a += wr[k] * h1[k];
            h2[tid] = (a >= 0.0f) ? a : 0.1f * a;
        }
        __syncthreads();
        if (tid < 4) {
            float a = b3[tid];
            const float* wr = W3 + tid * 128;
            for (int k = 0; k < 128; ++k) a += wr[k] * h2[k];
            res[b][4 + tid] = a;
        }
        __syncthreads();
        if (tid == 0) {
            const float r_out = res[b][4], yv = res[b][5], xv = res[b][6], zv = res[b][7];
            const float t2 = r_out * D2R;
            const float c2 = cosf(t2), s2 = sinf(t2);
            float* m = out + 1 + b * 16;
            m[0] = c2;  m[1] = 0.0f; m[2] = s2;  m[3] = -xv;
            m[4] = 0.0f; m[5] = 1.0f; m[6] = 0.0f; m[7] = -yv;
            m[8] = -s2; m[9] = 0.0f; m[10] = c2; m[11] = -zv;
            m[12] = 0.0f; m[13] = 0.0f; m[14] = 0.0f; m[15] = 1.0f;
            params[b * 8 + 0] = c2;
            params[b * 8 + 1] = s2;
            params[b * 8 + 2] = c2 * xv - s2 * zv;
            params[b * 8 + 3] = yv;
            params[b * 8 + 4] = s2 * xv + c2 * zv;
            res[b][0] = -xv; res[b][1] = -yv; res[b][2] = -zv;
            res[b][3] = atan2f(s2, c2) * R2D;
        }
        __syncthreads();
    }

    if (tid == 0) {
        float tl2 = 0.0f, dl2 = 0.0f;
        for (int b = 0; b < NB; ++b) {
            const float* g = camg + b * 16;
            const float dx = res[b][0] - g[3];
            const float dy = res[b][1] - g[7];
            const float dz = res[b][2] - g[11];
            tl2 += dx * dx + dy * dy + dz * dz;
            const float dg = atan2f(g[2], g[10]) * R2D;
            const float dd = res[b][3] - dg;
            dl2 += dd * dd;
        }
        out[0] = tl2 * 0.25f + dl2 * 0.25f;
    }
}

// ---------------------------------------------------------------------------
// Kernel 3: warp feat1 by estimated transform -> feat1_warped (d_out + 65).
// ---------------------------------------------------------------------------
__global__ __launch_bounds__(256) void k_warp(const float* __restrict__ feat1,
                                              const float* __restrict__ params,
                                              float* __restrict__ outw)
{
    const int b = blockIdx.y;
    const int p = (int)blockIdx.x * 256 + (int)threadIdx.x;
    const int z = p >> 11;
    const int y = (p >> 6) & 31;
    const int x = p & 63;

    const float cs = params[b * 8 + 0], sn = params[b * 8 + 1];
    const float tpx = params[b * 8 + 2], tpy = params[b * 8 + 3], tpz = params[b * 8 + 4];

    const float rx = (float)x - 31.5f;
    const float ry = (float)y - 15.5f;
    const float rz = (float)z - 31.5f;
    const float sx = cs * rx - sn * rz + tpx + 31.5f;
    const float sy = ry + tpy + 15.5f;
    const float sz = sn * rx + cs * rz + tpz + 31.5f;

    const float xf = floorf(sx), yf = floorf(sy), zf = floorf(sz);
    const float fx = sx - xf, fy = sy - yf, fz = sz - zf;
    const int ix = (int)xf, iy = (int)yf, iz = (int)zf;

    const float wx[2] = {1.0f - fx, fx};
    const float wy[2] = {1.0f - fy, fy};
    const float wz[2] = {1.0f - fz, fz};
    const int xs[2] = {min(max(ix, 0), 63), min(max(ix + 1, 0), 63)};
    const int ys[2] = {min(max(iy, 0), 31), min(max(iy + 1, 0), 31)};
    const int zs[2] = {min(max(iz, 0), 63), min(max(iz + 1, 0), 63)};
    const bool vx[2] = {(unsigned)ix < 64u, (unsigned)(ix + 1) < 64u};
    const bool vy[2] = {(unsigned)iy < 32u, (unsigned)(iy + 1) < 32u};
    const bool vz[2] = {(unsigned)iz < 64u, (unsigned)(iz + 1) < 64u};

    int idx[8]; float w[8];
    int q = 0;
    #pragma unroll
    for (int dz = 0; dz < 2; ++dz)
        #pragma unroll
        for (int dy = 0; dy < 2; ++dy)
            #pragma unroll
            for (int dx = 0; dx < 2; ++dx) {
                idx[q] = zs[dz] * 2048 + ys[dy] * 64 + xs[dx];
                w[q] = (vx[dx] && vy[dy] && vz[dz]) ? wx[dx] * wy[dy] * wz[dz] : 0.0f;
                ++q;
            }

    const float* f1b = feat1 + (size_t)b * NCH * CHV;
    float* ob = outw + (size_t)b * NCH * CHV;
    #pragma unroll 1
    for (int c = 0; c < NCH; ++c) {
        const float* f1c = f1b + (size_t)c * CHV;
        float a = 0.0f;
        #pragma unroll
        for (int k = 0; k < 8; ++k) a += w[k] * f1c[idx[k]];
        ob[(size_t)c * CHV + p] = a;
    }
}

// ---------------------------------------------------------------------------
extern "C" void kernel_launch(void* const* d_in, const int* in_sizes, int n_in,
                              void* d_out, int out_size, void* d_ws, size_t ws_size,
                              hipStream_t stream)
{
    (void)in_sizes; (void)n_in; (void)out_size; (void)ws_size;
    const float* feat0 = (const float*)d_in[0];
    const float* feat1 = (const float*)d_in[1];
    const float* camg  = (const float*)d_in[2];
    const float* W1 = (const float*)d_in[3];
    const float* b1 = (const float*)d_in[4];
    const float* W2 = (const float*)d_in[5];
    const float* b2 = (const float*)d_in[6];
    const float* W3 = (const float*)d_in[7];
    const float* b3 = (const float*)d_in[8];
    float* out = (float*)d_out;

    float* partial = (float*)d_ws;                 // 324*512 floats ~ 663 KB
    float* params  = partial + 324 * NT2;          // 32 floats

    hipLaunchKernelGGL(k_heat, dim3(2048), dim3(256), 0, stream,
                       feat0, feat1, partial);
    hipLaunchKernelGGL(k_mlp, dim3(1), dim3(256), 0, stream,
                       partial, camg, W1, b1, W2, b2, W3, b3, out, params);
    dim3 g3((64*32*64) / 256, NB);
    hipLaunchKernelGGL(k_warp, g3, dim3(256), 0, stream, feat1, params, out + 65);
}

// Round 11
// 257.646 us; speedup vs baseline: 1.1289x; 1.1289x over previous
//
#include <hip/hip_runtime.h>
#include <math.h>

#define NCH 32
#define CHV (64*32*64)      // one channel volume
#define NB 4
#define NT2 512             // tile-slots per n: 32zt * 8yt * 2chh
#define INVC (1.0f/(32.0f+1e-6f))
#define D2R 0.017453292519943295f
#define R2D 57.29577951308232f

// ---------------------------------------------------------------------------
// Kernel 1: fused rotate-warp(feat1) x 27-offset correlation vs feat0.
// Block = (b, chh, 2z x 4y x 64x tile): 192 threads = 3 independent waves,
// one per rotation (wave 1 = identity). NO LDS, NO barriers, NO stager:
// both feat0 rows and feat1 bilinear corners are read direct from global
// (L1/L2-resident; XCD-pinned working set). Waves free-run across channels,
// hiding latency without block lockstep.
// Bilinear x-edges: bx=clamp(ix,0,62) with re-derived (wxa,wxb) so sample is
// always wxa*f[bx] + wxb*f[bx+1]; z via masked wza/wzb + clamped rows.
// ---------------------------------------------------------------------------
__global__ __launch_bounds__(192) void k_heat(const float* __restrict__ feat0,
                                              const float* __restrict__ feat1,
                                              float* __restrict__ partial)
{
    // XCD-chunked remap: XCD x gets 256 consecutive nids = exactly one (b,chh)
    const int lid = (int)blockIdx.x;            // 0..2047
    const int nid = (lid & 7) * 256 + (lid >> 3);
    const int yt  = nid & 7;
    const int zt  = (nid >> 3) & 31;
    const int chh = (nid >> 8) & 1;
    const int b   = nid >> 9;

    const int tid = (int)threadIdx.x;
    const int wv = tid >> 6;           // rotation 0,1,2 (1 = identity)
    const int lane = tid & 63;
    const int tx = lane & 15, ty = lane >> 4;
    const int x0 = 4 * tx;
    const int y  = 4 * yt + ty;
    const int z0 = 2 * zt;             // thread owns z0, z0+1
    const bool yedge = (yt == 0) || (yt == 7);
    const bool ident = (wv == 1);

    const float* f0base = feat0 + ((size_t)b * NCH + chh * 16) * CHV;
    const float* f1base = feat1 + ((size_t)b * NCH + chh * 16) * CHV;

    // ---- bilinear gather setup (channel-invariant); identity wave skips ----
    int aLo[2][4], aHi[2][4];
    float wxa[2][4], wxb[2][4], wza[2][4], wzb[2][4];
    if (!ident) {
        const float th = 4.0f * (float)(wv - 1) * D2R;
        const float cs = cosf(th), sn = sinf(th);
        #pragma unroll
        for (int k = 0; k < 2; ++k) {
            #pragma unroll
            for (int i = 0; i < 4; ++i) {
                const float rx = (float)(x0 + i) - 31.5f;
                const float rz = (float)(z0 + k) - 31.5f;
                const float sx = cs * rx - sn * rz + 31.5f;
                const float sz = sn * rx + cs * rz + 31.5f;
                const float xf = floorf(sx), zf = floorf(sz);
                const float fx = sx - xf, fz = sz - zf;
                const int ix = (int)xf, iz = (int)zf;
                const float W0 = ((unsigned)ix < 64u) ? (1.0f - fx) : 0.0f;
                const float W1 = ((unsigned)(ix + 1) < 64u) ? fx : 0.0f;
                // bx in [0,62]; sample = wxa*f[bx] + wxb*f[bx+1] covers all cases
                int bx; float A_, B_;
                if (ix < 0)       { bx = 0;  A_ = W1;   B_ = 0.0f; } // f[0]=f[ix+1]
                else if (ix > 62) { bx = 62; A_ = 0.0f; B_ = W0;  } // f[63]=f[ix]
                else              { bx = ix; A_ = W0;   B_ = W1;  }
                wxa[k][i] = A_; wxb[k][i] = B_;
                wza[k][i] = ((unsigned)iz < 64u) ? (1.0f - fz) : 0.0f;
                wzb[k][i] = ((unsigned)(iz + 1) < 64u) ? fz : 0.0f;
                const int rowoff = y * 64 + bx;
                aLo[k][i] = min(max(iz, 0), 63) * 2048 + rowoff;
                aHi[k][i] = min(max(iz + 1, 0), 63) * 2048 + rowoff;
            }
        }
    }
    const int iA = z0 * 2048 + y * 64 + x0;   // identity rows (z0, z0+1 via +2048)

    // y-row masks + clamped offsets incl. x0 (channel-invariant, per lane)
    float myv[3]; int yoffc[3];
    #pragma unroll
    for (int yri = 0; yri < 3; ++yri) {
        const int yy = y - 1 + yri;
        myv[yri] = ((unsigned)yy < 32u) ? 1.0f : 0.0f;
        yoffc[yri] = min(max(yy, 0), 31) * 64 + x0;
    }

    float acc[27];
    #pragma unroll
    for (int o = 0; o < 27; ++o) acc[o] = 0.0f;

    #pragma unroll 1
    for (int ch = 0; ch < 16; ++ch) {
        const float* f1c = f1base + (size_t)ch * CHV;
        const float* f0c = f0base + (size_t)ch * CHV;

        // ---- featN sample: fr[k][i] for owned voxels ----
        float fr[2][4];
        if (ident) {
            const float4 v0 = *(const float4*)(f1c + iA);
            const float4 v1 = *(const float4*)(f1c + iA + 2048);
            fr[0][0] = v0.x; fr[0][1] = v0.y; fr[0][2] = v0.z; fr[0][3] = v0.w;
            fr[1][0] = v1.x; fr[1][1] = v1.y; fr[1][2] = v1.z; fr[1][3] = v1.w;
        } else {
            #pragma unroll
            for (int k = 0; k < 2; ++k) {
                #pragma unroll
                for (int i = 0; i < 4; ++i) {
                    const float vA = f1c[aLo[k][i]];
                    const float vB = f1c[aLo[k][i] + 1];
                    const float vC = f1c[aHi[k][i]];
                    const float vD = f1c[aHi[k][i] + 1];
                    const float sLo = wxa[k][i] * vA + wxb[k][i] * vB;
                    const float sHi = wxa[k][i] * vC + wxb[k][i] * vD;
                    fr[k][i] = wza[k][i] * sLo + wzb[k][i] * sHi;
                }
            }
        }

        // ---- featN x-extension (4 shuffles/ch; featN pads with zeros) ----
        float g0[2], g5[2];
        #pragma unroll
        for (int k = 0; k < 2; ++k) {
            const float a = __shfl_up(fr[k][3], 1, 64);
            const float c = __shfl_down(fr[k][0], 1, 64);
            g0[k] = (tx == 0) ? 0.0f : a;
            g5[k] = (tx == 15) ? 0.0f : c;
        }

        // ---- correlation: 12 feat0 rows direct from global ----
#define ROWFMA(KK, OZP1, YRI)                                                   \
        { const int base_ = (OZP1) * 9 + (2 - (YRI)) * 3;                       \
          acc[base_ + 0] += g0[KK]*R.x + fr[KK][0]*R.y + fr[KK][1]*R.z + fr[KK][2]*R.w; \
          acc[base_ + 1] += fr[KK][0]*R.x + fr[KK][1]*R.y + fr[KK][2]*R.z + fr[KK][3]*R.w; \
          acc[base_ + 2] += fr[KK][1]*R.x + fr[KK][2]*R.y + fr[KK][3]*R.z + g5[KK]*R.w; }
#define CORRLOOP(MASKED)                                                        \
        _Pragma("unroll")                                                       \
        for (int zri = 0; zri < 4; ++zri) {                                     \
            const int zz = 2 * zt - 1 + zri;                                    \
            if (zz >= 0 && zz <= 63) {                                          \
                const float* rp = f0c + zz * 2048;                              \
                _Pragma("unroll")                                               \
                for (int yri = 0; yri < 3; ++yri) {                             \
                    float4 R = *(const float4*)(rp + yoffc[yri]);               \
                    if (MASKED) { const float m_ = myv[yri];                    \
                        R.x *= m_; R.y *= m_; R.z *= m_; R.w *= m_; }           \
                    if (zri == 0) { ROWFMA(0, 2, yri) }                         \
                    if (zri == 1) { ROWFMA(0, 1, yri) ROWFMA(1, 2, yri) }       \
                    if (zri == 2) { ROWFMA(0, 0, yri) ROWFMA(1, 1, yri) }       \
                    if (zri == 3) { ROWFMA(1, 0, yri) }                         \
                }                                                               \
            }                                                                   \
        }
        if (yedge) { CORRLOOP(1) } else { CORRLOOP(0) }
#undef CORRLOOP
#undef ROWFMA
    }

    // ---- per-wave reduction (fixed order -> deterministic), direct write ----
    const int slot = (zt * 8 + yt) * 2 + chh;
    #pragma unroll 1
    for (int o = 0; o < 27; ++o) {
        float v = acc[o];
        #pragma unroll
        for (int d = 32; d >= 1; d >>= 1) v += __shfl_down(v, d, 64);
        if (lane == 0)
            partial[((size_t)((b * 3 + wv) * 27) + o) * NT2 + slot] = v;
    }
}

// ---------------------------------------------------------------------------
// Kernel 2: reduce partials (transposed layout: [n*27][512] rows, vectorized)
// -> heat, per-batch MLP, loss + matrices + params.
// ---------------------------------------------------------------------------
__global__ __launch_bounds__(256) void k_mlp(const float* __restrict__ partial,
                                             const float* __restrict__ camg,
                                             const float* __restrict__ W1,
                                             const float* __restrict__ b1,
                                             const float* __restrict__ W2,
                                             const float* __restrict__ b2,
                                             const float* __restrict__ W3,
                                             const float* __restrict__ b3,
                                             float* __restrict__ out,
                                             float* __restrict__ params)
{
    __shared__ float heat[324];
    __shared__ float f[81];
    __shared__ float h1[128];
    __shared__ float h2[128];
    __shared__ float denom_s;
    __shared__ float res[NB][8];
    const int tid = (int)threadIdx.x;

    for (int r = tid; r < 324; r += 256) {
        const float4* p = (const float4*)(partial + (size_t)r * NT2);
        float s0 = 0.0f, s1 = 0.0f, s2 = 0.0f, s3 = 0.0f;
        #pragma unroll 4
        for (int i = 0; i < NT2 / 4; ++i) {
            const float4 v = p[i];
            s0 += v.x; s1 += v.y; s2 += v.z; s3 += v.w;
        }
        heat[r] = ((s0 + s1) + (s2 + s3)) * INVC;
    }
    __syncthreads();

    for (int b = 0; b < NB; ++b) {
        if (tid < 81) {
            float v = heat[b * 81 + tid];
            f[tid] = (v >= 0.0f) ? v : 0.1f * v;
        }
        __syncthreads();
        if (tid == 0) {
            float ss = 0.0f;
            for (int k = 0; k < 81; ++k) ss += f[k] * f[k];
            denom_s = 1e-6f + sqrtf(ss);
        }
        __syncthreads();
        if (tid < 81) f[tid] = f[tid] / denom_s;
        __syncthreads();
        if (tid < 128) {
            float a = b1[tid];
            const float* wr = W1 + tid * 81;
            for (int k = 0; k < 81; ++k) a += wr[k] * f[k];
            h1[tid] = (a >= 0.0f) ? a : 0.1f * a;
        }
        __syncthreads();
        if (tid < 128) {
            float a = b2[tid];
            const float* wr = W2 + tid * 128;
            for (int k = 0; k < 128; ++k) a += wr[k] * h1[k];
            h2[tid] = (a >= 0.0f) ? a : 0.1f * a;
        }
        __syncthreads();
        if (tid < 4) {
            float a = b3[tid];
            const float* wr = W3 + tid * 128;
            for (int k = 0; k < 128; ++k) a += wr[k] * h2[k];
            res[b][4 + tid] = a;
        }
        __syncthreads();
        if (tid == 0) {
            const float r_out = res[b][4], yv = res[b][5], xv = res[b][6], zv = res[b][7];
            const float t2 = r_out * D2R;
            const float c2 = cosf(t2), s2 = sinf(t2);
            float* m = out + 1 + b * 16;
            m[0] = c2;  m[1] = 0.0f; m[2] = s2;  m[3] = -xv;
            m[4] = 0.0f; m[5] = 1.0f; m[6] = 0.0f; m[7] = -yv;
            m[8] = -s2; m[9] = 0.0f; m[10] = c2; m[11] = -zv;
            m[12] = 0.0f; m[13] = 0.0f; m[14] = 0.0f; m[15] = 1.0f;
            params[b * 8 + 0] = c2;
            params[b * 8 + 1] = s2;
            params[b * 8 + 2] = c2 * xv - s2 * zv;
            params[b * 8 + 3] = yv;
            params[b * 8 + 4] = s2 * xv + c2 * zv;
            res[b][0] = -xv; res[b][1] = -yv; res[b][2] = -zv;
            res[b][3] = atan2f(s2, c2) * R2D;
        }
        __syncthreads();
    }

    if (tid == 0) {
        float tl2 = 0.0f, dl2 = 0.0f;
        for (int b = 0; b < NB; ++b) {
            const float* g = camg + b * 16;
            const float dx = res[b][0] - g[3];
            const float dy = res[b][1] - g[7];
            const float dz = res[b][2] - g[11];
            tl2 += dx * dx + dy * dy + dz * dz;
            const float dg = atan2f(g[2], g[10]) * R2D;
            const float dd = res[b][3] - dg;
            dl2 += dd * dd;
        }
        out[0] = tl2 * 0.25f + dl2 * 0.25f;
    }
}

// ---------------------------------------------------------------------------
// Kernel 3: warp feat1 by estimated transform -> feat1_warped (d_out + 65).
// ---------------------------------------------------------------------------
__global__ __launch_bounds__(256) void k_warp(const float* __restrict__ feat1,
                                              const float* __restrict__ params,
                                              float* __restrict__ outw)
{
    const int b = blockIdx.y;
    const int p = (int)blockIdx.x * 256 + (int)threadIdx.x;
    const int z = p >> 11;
    const int y = (p >> 6) & 31;
    const int x = p & 63;

    const float cs = params[b * 8 + 0], sn = params[b * 8 + 1];
    const float tpx = params[b * 8 + 2], tpy = params[b * 8 + 3], tpz = params[b * 8 + 4];

    const float rx = (float)x - 31.5f;
    const float ry = (float)y - 15.5f;
    const float rz = (float)z - 31.5f;
    const float sx = cs * rx - sn * rz + tpx + 31.5f;
    const float sy = ry + tpy + 15.5f;
    const float sz = sn * rx + cs * rz + tpz + 31.5f;

    const float xf = floorf(sx), yf = floorf(sy), zf = floorf(sz);
    const float fx = sx - xf, fy = sy - yf, fz = sz - zf;
    const int ix = (int)xf, iy = (int)yf, iz = (int)zf;

    const float wx[2] = {1.0f - fx, fx};
    const float wy[2] = {1.0f - fy, fy};
    const float wz[2] = {1.0f - fz, fz};
    const int xs[2] = {min(max(ix, 0), 63), min(max(ix + 1, 0), 63)};
    const int ys[2] = {min(max(iy, 0), 31), min(max(iy + 1, 0), 31)};
    const int zs[2] = {min(max(iz, 0), 63), min(max(iz + 1, 0), 63)};
    const bool vx[2] = {(unsigned)ix < 64u, (unsigned)(ix + 1) < 64u};
    const bool vy[2] = {(unsigned)iy < 32u, (unsigned)(iy + 1) < 32u};
    const bool vz[2] = {(unsigned)iz < 64u, (unsigned)(iz + 1) < 64u};

    int idx[8]; float w[8];
    int q = 0;
    #pragma unroll
    for (int dz = 0; dz < 2; ++dz)
        #pragma unroll
        for (int dy = 0; dy < 2; ++dy)
            #pragma unroll
            for (int dx = 0; dx < 2; ++dx) {
                idx[q] = zs[dz] * 2048 + ys[dy] * 64 + xs[dx];
                w[q] = (vx[dx] && vy[dy] && vz[dz]) ? wx[dx] * wy[dy] * wz[dz] : 0.0f;
                ++q;
            }

    const float* f1b = feat1 + (size_t)b * NCH * CHV;
    float* ob = outw + (size_t)b * NCH * CHV;
    #pragma unroll 1
    for (int c = 0; c < NCH; ++c) {
        const float* f1c = f1b + (size_t)c * CHV;
        float a = 0.0f;
        #pragma unroll
        for (int k = 0; k < 8; ++k) a += w[k] * f1c[idx[k]];
        ob[(size_t)c * CHV + p] = a;
    }
}

// ---------------------------------------------------------------------------
extern "C" void kernel_launch(void* const* d_in, const int* in_sizes, int n_in,
                              void* d_out, int out_size, void* d_ws, size_t ws_size,
                              hipStream_t stream)
{
    (void)in_sizes; (void)n_in; (void)out_size; (void)ws_size;
    const float* feat0 = (const float*)d_in[0];
    const float* feat1 = (const float*)d_in[1];
    const float* camg  = (const float*)d_in[2];
    const float* W1 = (const float*)d_in[3];
    const float* b1 = (const float*)d_in[4];
    const float* W2 = (const float*)d_in[5];
    const float* b2 = (const float*)d_in[6];
    const float* W3 = (const float*)d_in[7];
    const float* b3 = (const float*)d_in[8];
    float* out = (float*)d_out;

    float* partial = (float*)d_ws;                 // 324*512 floats ~ 663 KB
    float* params  = partial + 324 * NT2;          // 32 floats

    hipLaunchKernelGGL(k_heat, dim3(2048), dim3(192), 0, stream,
                       feat0, feat1, partial);
    hipLaunchKernelGGL(k_mlp, dim3(1), dim3(256), 0, stream,
                       partial, camg, W1, b1, W2, b2, W3, b3, out, params);
    dim3 g3((64*32*64) / 256, NB);
    hipLaunchKernelGGL(k_warp, g3, dim3(256), 0, stream, feat1, params, out + 65);
}